// Round 3
// baseline (21198.843 us; speedup 1.0000x reference)
//
#include <hip/hip_runtime.h>

// LSTM: S=512, B=64, I=256, H=1024. Round 3: ALL FP32 (inputs and output),
// per the reference dtypes. The round-1/2 NaNs are explained by reading fp32
// buffers as bf16 (random low-mantissa halves decode to Inf/NaN bf16).
// Structure: one launch per timestep (512 launches); fused input projection
// (K = 1024 h-chunks + 256 x-chunks); LDS-tiled scalar FMA (no MFMA for fp32
// on CDNA4). Block = 16 batch x 16 hidden, all 4 gates; f32 cell state in ws;
// h feedback via fp32 h_seq slice of d_out.

#define SEQ   512
#define BATCH 64
#define ISZ   256
#define HID   1024

__global__ __launch_bounds__(256) void lstm_step(
    const float* __restrict__ x,
    const float* __restrict__ Wfx, const float* __restrict__ bfx,
    const float* __restrict__ Wix, const float* __restrict__ bix,
    const float* __restrict__ Wgx, const float* __restrict__ bgx,
    const float* __restrict__ Wox, const float* __restrict__ box_,
    const float* __restrict__ Wfh, const float* __restrict__ bfh,
    const float* __restrict__ Wih, const float* __restrict__ bih,
    const float* __restrict__ Wgh, const float* __restrict__ bgh,
    const float* __restrict__ Woh, const float* __restrict__ boh,
    float* out,                       // h_seq [512][64][1024], h [64][1024], c [64][1024]
    float* __restrict__ c_ws,         // [64][1024] f32 running cell state
    int s)
{
    __shared__ __align__(16) float Ash[16][68];       // 16 batch rows x 64 k (+4 pad)
    __shared__ __align__(16) float Wsh[4][16][68];    // 4 gates x 16 n x 64 k (+4 pad)

    const int t    = threadIdx.x;
    const int lane = t & 63;
    const int w    = t >> 6;          // wave id == gate id for W staging
    const int hb   = blockIdx.x;      // 0..63: hidden dims hb*16..+16
    const int bm   = blockIdx.y;      // 0..3 : batch rows bm*16..+16
    const int bl   = t >> 4;          // 0..15 local batch (compute mapping)
    const int nl   = t & 15;          // 0..15 local hidden

    const float* Wh_[4] = {Wfh, Wih, Wgh, Woh};
    const float* Wx_[4] = {Wfx, Wix, Wgx, Wox};

    const float* hprev = out + (size_t)(s - 1) * (BATCH * HID);  // valid if s>0
    const int ch0 = (s == 0) ? 16 : 0;    // s==0: h is zero, skip h chunks

    float af = 0.f, ai = 0.f, ag = 0.f, ao = 0.f;

    for (int ch = ch0; ch < 20; ++ch) {   // 0..15: h (K=1024), 16..19: x (K=256)
        __syncthreads();
        {   // A tile: 16 rows x 64 floats; thread -> row=t>>4, 1 float4
            int row = t >> 4, e = (t & 15) * 4;
            const float* src = (ch < 16)
                ? hprev + (size_t)(bm * 16 + row) * HID + ch * 64 + e
                : x + (size_t)s * (BATCH * ISZ) + (size_t)(bm * 16 + row) * ISZ + (ch - 16) * 64 + e;
            *(float4*)&Ash[row][e] = *(const float4*)src;
        }
        {   // W tile: wave w stages gate w: 16 rows x 64 floats, 4x float4/lane
            int row = lane >> 2, e0 = (lane & 3) * 16;
            int n = hb * 16 + row;
            const float* srcw = (ch < 16)
                ? Wh_[w] + (size_t)n * HID + ch * 64 + e0
                : Wx_[w] + (size_t)n * ISZ + (ch - 16) * 64 + e0;
            *(float4*)&Wsh[w][row][e0]      = *(const float4*)(srcw);
            *(float4*)&Wsh[w][row][e0 + 4]  = *(const float4*)(srcw + 4);
            *(float4*)&Wsh[w][row][e0 + 8]  = *(const float4*)(srcw + 8);
            *(float4*)&Wsh[w][row][e0 + 12] = *(const float4*)(srcw + 12);
        }
        __syncthreads();
#pragma unroll
        for (int k = 0; k < 64; k += 4) {
            float4 av = *(const float4*)&Ash[bl][k];
            float4 vf = *(const float4*)&Wsh[0][nl][k];
            float4 vi = *(const float4*)&Wsh[1][nl][k];
            float4 vg = *(const float4*)&Wsh[2][nl][k];
            float4 vo = *(const float4*)&Wsh[3][nl][k];
            af += av.x * vf.x + av.y * vf.y + av.z * vf.z + av.w * vf.w;
            ai += av.x * vi.x + av.y * vi.y + av.z * vi.z + av.w * vi.w;
            ag += av.x * vg.x + av.y * vg.y + av.z * vg.z + av.w * vg.w;
            ao += av.x * vo.x + av.y * vo.y + av.z * vo.z + av.w * vo.w;
        }
    }

    // epilogue: thread (bl, nl) owns (b, n)
    const int b = bm * 16 + bl;
    const int n = hb * 16 + nl;

    af += bfh[n] + bfx[n];
    ai += bih[n] + bix[n];
    ag += bgh[n] + bgx[n];
    ao += boh[n] + box_[n];

    float fg = 1.f / (1.f + __expf(-af));
    float ig = 1.f / (1.f + __expf(-ai));
    float gg = 1.f - 2.f / (1.f + __expf(2.f * ag));
    float og = 1.f / (1.f + __expf(-ao));

    float c_old = (s == 0) ? 0.f : c_ws[(size_t)b * HID + n];
    float c_new = c_old * fg + ig * gg;
    c_ws[(size_t)b * HID + n] = c_new;
    float h = (1.f - 2.f / (1.f + __expf(2.f * c_new))) * og;

    out[(size_t)s * (BATCH * HID) + (size_t)b * HID + n] = h;
    if (s == SEQ - 1) {
        out[(size_t)SEQ * (BATCH * HID) + (size_t)b * HID + n] = h;
        out[(size_t)SEQ * (BATCH * HID) + (BATCH * HID) + (size_t)b * HID + n] = c_new;
    }
}

extern "C" void kernel_launch(void* const* d_in, const int* in_sizes, int n_in,
                              void* d_out, int out_size, void* d_ws, size_t ws_size,
                              hipStream_t stream) {
    const float* x   = (const float*)d_in[0];
    const float* Wfx = (const float*)d_in[1];
    const float* bfx = (const float*)d_in[2];
    const float* Wix = (const float*)d_in[3];
    const float* bix = (const float*)d_in[4];
    const float* Wgx = (const float*)d_in[5];
    const float* bgx = (const float*)d_in[6];
    const float* Wox = (const float*)d_in[7];
    const float* box_= (const float*)d_in[8];
    const float* Wfh = (const float*)d_in[9];
    const float* bfh = (const float*)d_in[10];
    const float* Wih = (const float*)d_in[11];
    const float* bih = (const float*)d_in[12];
    const float* Wgh = (const float*)d_in[13];
    const float* bgh = (const float*)d_in[14];
    const float* Woh = (const float*)d_in[15];
    const float* boh = (const float*)d_in[16];
    float* out  = (float*)d_out;
    float* c_ws = (float*)d_ws;   // 64*1024*4 = 256 KB

    dim3 grid(64, 4);             // 64 hidden-tiles x 4 batch-tiles = 256 blocks
    for (int s = 0; s < SEQ; ++s)
        lstm_step<<<grid, 256, 0, stream>>>(
            x, Wfx, bfx, Wix, bix, Wgx, bgx, Wox, box_,
            Wfh, bfh, Wih, bih, Wgh, bgh, Woh, boh,
            out, c_ws, s);
}

// Round 4
// 6451.826 us; speedup vs baseline: 3.2857x; 3.2857x over previous
//
#include <hip/hip_runtime.h>
#include <hip/hip_bf16.h>

// LSTM: S=512, B=64, I=256, H=1024, fp32 in/out. Round 4: bf16 MFMA, no-LDS K-loop.
// - prep kernel: all 8 W (fp32) -> bf16, pre-swizzled into MFMA B-frag order in ws
//   (coalesced dwordx4 frag loads, no LDS staging, no barriers in K-loop)
// - 512 step launches; K = 1024 (h, bf16 ring buffer in ws) + 256 (x, fp32->bf16 inline)
// - grid 256 blocks x 4 waves; wave = 16M x 16cols frag (cols gate-interleaved n*4+g)
// - f32 accumulate (MFMA), f32 cell state in ws, f32 h_seq to out; h bf16 copy to ws

#define SEQ   512
#define BATCH 64
#define ISZ   256
#define HID   1024
#define NCOL  4096            // 4 gates * HID; col = n*4 + gate (f,i,g,o)
#define KH    1024
#define KTOT  1280
#define NKS   40              // K-steps of 32
#define NKSH  32              // h-part K-steps

typedef __attribute__((ext_vector_type(8))) short bf16x8;
typedef __attribute__((ext_vector_type(4))) float f32x4;
typedef unsigned short u16;

#define WSW_ELEMS  ((size_t)NCOL * KTOT)        // 5,242,880 bf16 = 10.5 MB
#define HBUF_ELEMS ((size_t)2 * BATCH * HID)    // 131,072 bf16  = 256 KB

__device__ __forceinline__ u16 f2bf(float f) {
    union { float f; unsigned int u; } c; c.f = f;
    unsigned int u = c.u;
    u += 0x7fffu + ((u >> 16) & 1u);            // RNE (inputs finite)
    return (u16)(u >> 16);
}

struct WPtrs { const float* Wh[4]; const float* Wx[4]; };

// Wsw[cg][ks][lane][j]: lane=(q<<4)|nl -> col=cg*16+nl, k=ks*32+q*8+j
__global__ __launch_bounds__(256) void build_w(WPtrs wp, u16* __restrict__ Wsw) {
    size_t did = (size_t)blockIdx.x * 256 + threadIdx.x;    // one 16B group each
    if (did >= WSW_ELEMS / 8) return;
    int lane = (int)(did & 63);
    size_t rest = did >> 6;
    int ks = (int)(rest % NKS);
    int cg = (int)(rest / NKS);
    int nl = lane & 15, q = lane >> 4;
    int col = cg * 16 + nl;
    int g = col & 3, n = col >> 2;
    int k0 = ks * 32 + q * 8;
    const float* src = (k0 < KH) ? wp.Wh[g] + (size_t)n * KH + k0
                                 : wp.Wx[g] + (size_t)n * ISZ + (k0 - KH);
    u16 tmp[8];
#pragma unroll
    for (int j = 0; j < 8; ++j) tmp[j] = f2bf(src[j]);
    *(bf16x8*)(Wsw + did * 8) = *(const bf16x8*)tmp;        // did*16 B, aligned
}

struct StepP {
    const float* x;
    const float* bfh; const float* bfx;
    const float* bih; const float* bix;
    const float* bgh; const float* bgx;
    const float* boh; const float* box;
    const u16* Wsw;
    u16* hbuf;        // [2][64][1024] bf16 ring
    float* c_ws;      // [64][1024] f32
    float* out;       // h_seq, h_final, c_final (fp32)
};

__global__ __launch_bounds__(256) void lstm_step(StepP p, int s) {
    __shared__ float Gsh[4][16][20];     // per-wave D exchange (pad 20: 16B-aligned rows)

    const int t    = threadIdx.x;
    const int lane = t & 63;
    const int w    = t >> 6;             // wave: batch rows w*16..+16
    const int cg   = blockIdx.x;         // col group: cols cg*16..+16
    const int ml   = lane & 15;          // A row / D col index
    const int q    = lane >> 4;          // quad
    const int arow = w * 16 + ml;        // global batch row for A-frags

    const u16* hrd = p.hbuf + (size_t)(s & 1) * (BATCH * HID);
    u16*       hwr = p.hbuf + (size_t)((s + 1) & 1) * (BATCH * HID);

    const u16* Bp = p.Wsw + (size_t)cg * (NKS * 64 * 8) + (size_t)lane * 8;
    f32x4 acc = {0.f, 0.f, 0.f, 0.f};

    if (s > 0) {                          // h part: K = 0..1023
        const u16* Ap = hrd + (size_t)arow * HID + q * 8;
#pragma unroll 8
        for (int ks = 0; ks < NKSH; ++ks) {
            bf16x8 a = *(const bf16x8*)(Ap + ks * 32);
            bf16x8 b = *(const bf16x8*)(Bp + (size_t)ks * 512);
            acc = __builtin_amdgcn_mfma_f32_16x16x32_bf16(a, b, acc, 0, 0, 0);
        }
    }
    {                                     // x part: K = 1024..1279, fp32 -> bf16 inline
        const float* Xp = p.x + ((size_t)s * BATCH + arow) * ISZ + q * 8;
#pragma unroll
        for (int ks = 0; ks < 8; ++ks) {
            float4 x0 = *(const float4*)(Xp + ks * 32);
            float4 x1 = *(const float4*)(Xp + ks * 32 + 4);
            u16 ax[8] = { f2bf(x0.x), f2bf(x0.y), f2bf(x0.z), f2bf(x0.w),
                          f2bf(x1.x), f2bf(x1.y), f2bf(x1.z), f2bf(x1.w) };
            bf16x8 a = *(const bf16x8*)ax;
            bf16x8 b = *(const bf16x8*)(Bp + (size_t)(NKSH + ks) * 512);
            acc = __builtin_amdgcn_mfma_f32_16x16x32_bf16(a, b, acc, 0, 0, 0);
        }
    }

    // D layout: col = lane&15, row = q*4+r  (m89-verified)
#pragma unroll
    for (int r = 0; r < 4; ++r) Gsh[w][q * 4 + r][ml] = acc[r];
    __syncthreads();

    // epilogue: thread -> (b = w*16 + lane>>2, n = cg*4 + lane&3); gates contiguous
    const int row2 = lane >> 2;
    const int hl   = lane & 3;
    const int b    = w * 16 + row2;
    const int n    = cg * 4 + hl;
    float4 gv = *(const float4*)&Gsh[w][row2][hl * 4];   // f,i,g,o preacts

    float af = gv.x + p.bfh[n] + p.bfx[n];
    float ai = gv.y + p.bih[n] + p.bix[n];
    float ag = gv.z + p.bgh[n] + p.bgx[n];
    float ao = gv.w + p.boh[n] + p.box[n];

    float fg = 1.f / (1.f + __expf(-af));
    float ig = 1.f / (1.f + __expf(-ai));
    float gg = 1.f - 2.f / (1.f + __expf(2.f * ag));
    float og = 1.f / (1.f + __expf(-ao));

    float c_old = (s == 0) ? 0.f : p.c_ws[(size_t)b * HID + n];
    float c_new = c_old * fg + ig * gg;
    p.c_ws[(size_t)b * HID + n] = c_new;
    float h = (1.f - 2.f / (1.f + __expf(2.f * c_new))) * og;

    p.out[(size_t)s * (BATCH * HID) + (size_t)b * HID + n] = h;
    hwr[(size_t)b * HID + n] = f2bf(h);
    if (s == SEQ - 1) {
        p.out[(size_t)SEQ * (BATCH * HID) + (size_t)b * HID + n] = h;
        p.out[(size_t)SEQ * (BATCH * HID) + (BATCH * HID) + (size_t)b * HID + n] = c_new;
    }
}

extern "C" void kernel_launch(void* const* d_in, const int* in_sizes, int n_in,
                              void* d_out, int out_size, void* d_ws, size_t ws_size,
                              hipStream_t stream) {
    WPtrs wp;
    wp.Wx[0] = (const float*)d_in[1];  wp.Wx[1] = (const float*)d_in[3];
    wp.Wx[2] = (const float*)d_in[5];  wp.Wx[3] = (const float*)d_in[7];
    wp.Wh[0] = (const float*)d_in[9];  wp.Wh[1] = (const float*)d_in[11];
    wp.Wh[2] = (const float*)d_in[13]; wp.Wh[3] = (const float*)d_in[15];

    u16*   Wsw  = (u16*)d_ws;                               // 10.5 MB
    u16*   hbuf = Wsw + WSW_ELEMS;                          // 256 KB
    float* c_ws = (float*)(hbuf + HBUF_ELEMS);              // 256 KB (16B-aligned: even elem counts)

    StepP p;
    p.x    = (const float*)d_in[0];
    p.bfx  = (const float*)d_in[2];   p.bix  = (const float*)d_in[4];
    p.bgx  = (const float*)d_in[6];   p.box  = (const float*)d_in[8];
    p.bfh  = (const float*)d_in[10];  p.bih  = (const float*)d_in[12];
    p.bgh  = (const float*)d_in[14];  p.boh  = (const float*)d_in[16];
    p.Wsw  = Wsw;
    p.hbuf = hbuf;
    p.c_ws = c_ws;
    p.out  = (float*)d_out;

    build_w<<<dim3((unsigned)((WSW_ELEMS / 8 + 255) / 256)), 256, 0, stream>>>(wp, Wsw);
    for (int s = 0; s < SEQ; ++s)
        lstm_step<<<dim3(NCOL / 16), 256, 0, stream>>>(p, s);
}